// Round 4
// baseline (2362.782 us; speedup 1.0000x reference)
//
#include <hip/hip_runtime.h>

#define TOK 8192
#define DMODEL 768
#define NEXP 8
#define NSEG 29

typedef __attribute__((ext_vector_type(8))) short s16x8;
typedef __attribute__((ext_vector_type(4))) float fx4;

__device__ __forceinline__ float b2f(unsigned short u) {
    unsigned v = ((unsigned)u) << 16;
    return __builtin_bit_cast(float, v);
}
__device__ __forceinline__ unsigned short f2b(float f) {
    unsigned v = __builtin_bit_cast(unsigned, f);
    v += 0x7fffu + ((v >> 16) & 1u);
    return (unsigned short)(v >> 16);
}
__device__ __forceinline__ float gelu_f(float v) {
    // tanh-approx GELU (jax.nn.gelu approximate=True)
    float g = 0.7978845608028654f * (v + 0.044715f * v * v * v);
    float e = __expf(2.f * g);
    float th = 1.f - 2.f / (e + 1.f);   // overflow-safe tanh
    return 0.5f * v * (1.f + th);
}

struct SegTable {
    const float* src[NSEG];
    unsigned short* dst[NSEG];
    int n4[NSEG];
};

// ---------------- fp32 -> bf16 conversion (segments) ----------------
__global__ __launch_bounds__(256) void convert_kernel(SegTable st) {
    const int sg = blockIdx.y;
    const float4* __restrict__ src = (const float4*)st.src[sg];
    unsigned short* __restrict__ dst = st.dst[sg];
    const int n4 = st.n4[sg];
    for (int i = blockIdx.x * blockDim.x + threadIdx.x; i < n4; i += gridDim.x * blockDim.x) {
        float4 v = src[i];
        unsigned r0 = (unsigned)f2b(v.x) | ((unsigned)f2b(v.y) << 16);
        unsigned r1 = (unsigned)f2b(v.z) | ((unsigned)f2b(v.w) << 16);
        *(uint2*)&dst[(size_t)i * 4] = make_uint2(r0, r1);
    }
}

// ---------------- zero d_out + counters ----------------
__global__ __launch_bounds__(256) void zero_kernel(float* __restrict__ out,
                                                   unsigned* __restrict__ hdr) {
    int idx = blockIdx.x * blockDim.x + threadIdx.x;
    if (blockIdx.x == 0 && threadIdx.x < 16) hdr[threadIdx.x] = 0u;  // cnt[8] + Psum[8]
    float4 z = make_float4(0.f, 0.f, 0.f, 0.f);
    float4* p = (float4*)out;
    const int n4 = TOK * DMODEL / 4;
    for (int i = idx; i < n4; i += gridDim.x * blockDim.x) p[i] = z;
}

// ---------------- router (fp32, matches reference numerics closely) ----------------
__global__ __launch_bounds__(256) void router_kernel(
    const float* __restrict__ x, const float* __restrict__ Wg,
    int* __restrict__ cnt, float* __restrict__ Psum,
    int* __restrict__ lists, float* __restrict__ wlists, int rowcap)
{
    int t = blockIdx.x * 4 + (threadIdx.x >> 6);
    int lane = threadIdx.x & 63;
    if (t >= TOK) return;
    const float* xr = x + (size_t)t * DMODEL;
    float s[NEXP];
#pragma unroll
    for (int e = 0; e < NEXP; e++) s[e] = 0.f;
#pragma unroll
    for (int i = 0; i < 12; i++) {
        int d = lane + 64 * i;
        float xv = xr[d];
        float4 w0 = *(const float4*)&Wg[d * 8];
        float4 w1 = *(const float4*)&Wg[d * 8 + 4];
        s[0] += xv * w0.x; s[1] += xv * w0.y; s[2] += xv * w0.z; s[3] += xv * w0.w;
        s[4] += xv * w1.x; s[5] += xv * w1.y; s[6] += xv * w1.z; s[7] += xv * w1.w;
    }
#pragma unroll
    for (int off = 32; off >= 1; off >>= 1) {
#pragma unroll
        for (int e = 0; e < NEXP; e++) s[e] += __shfl_xor(s[e], off, 64);
    }
    float m = s[0];
#pragma unroll
    for (int e = 1; e < NEXP; e++) m = fmaxf(m, s[e]);
    float p[NEXP]; float sum = 0.f;
#pragma unroll
    for (int e = 0; e < NEXP; e++) { p[e] = __expf(s[e] - m); sum += p[e]; }
    float inv = 1.f / sum;
#pragma unroll
    for (int e = 0; e < NEXP; e++) p[e] *= inv;
    // top-2, lowest index wins ties (matches jax.lax.top_k)
    int i0 = 0;
    for (int e = 1; e < NEXP; e++) if (p[e] > p[i0]) i0 = e;
    int i1 = (i0 == 0) ? 1 : 0;
    for (int e = 0; e < NEXP; e++) if (e != i0 && p[e] > p[i1]) i1 = e;
    float wsum = p[i0] + p[i1];
    if (lane < NEXP) {
        float myp = p[0];                       // static-index select (avoid scratch)
#pragma unroll
        for (int e = 1; e < NEXP; e++) if (lane == e) myp = p[e];
        atomicAdd(&Psum[lane], myp);
    }
    if (lane == 0) {
        int pos0 = atomicAdd(&cnt[i0], 1);
        if (pos0 < rowcap) { lists[i0 * TOK + pos0] = t; wlists[i0 * TOK + pos0] = p[i0] / wsum; }
        int pos1 = atomicAdd(&cnt[i1], 1);
        if (pos1 < rowcap) { lists[i1 * TOK + pos1] = t; wlists[i1 * TOK + pos1] = p[i1] / wsum; }
    }
}

// ---------------- FFN layer 1: hidden = gelu(concat(x,extra) @ W1 + b1) ----------------
__global__ __launch_bounds__(256) void ffn1_kernel(
    const unsigned short* __restrict__ x, const unsigned short* __restrict__ extra,
    int edim, int estride,
    const unsigned short* __restrict__ W1, const unsigned short* __restrict__ bias1,
    unsigned short* __restrict__ hidden, int H, int ind,
    const int* __restrict__ cnt, int eidx, const int* __restrict__ lists, int rowcap)
{
    int count = cnt[eidx]; if (count > rowcap) count = rowcap;
    const int m0 = blockIdx.x * 64;
    if (m0 >= count) return;
    __shared__ __align__(16) unsigned short As[64][40];
    __shared__ __align__(16) unsigned short Bs[64][40];
    const int tid = threadIdx.x;
    const int ar = tid >> 2, ac0 = (tid & 3) * 8;
    const int t_st = lists[eidx * TOK + min(m0 + ar, count - 1)];
    const int br = tid >> 3, bc0 = (tid & 7) * 8;
    const int lane = tid & 63;
    const int wm = tid >> 7, wn = (tid >> 6) & 1;
    const int lrow = lane & 15, kfrag = (lane >> 4) * 8;
    const int n_glob0 = blockIdx.y * 64;
    fx4 acc[2][2] = {};
    const int nkt = (ind + 31) >> 5;
    for (int kt = 0; kt < nkt; ++kt) {
        const int kb = kt * 32;
        {   // A stage: 64x32 tile of concat(x, extra), zero-padded past ind
            int k = kb + ac0;
            uint4 v;
            if (k + 8 <= DMODEL) {
                v = *(const uint4*)&x[(size_t)t_st * DMODEL + k];
            } else {
                int kx = k - DMODEL;
                if (kx + 8 <= edim) {
                    v = *(const uint4*)&extra[(size_t)t_st * estride + kx];
                } else {
                    union { uint4 v4; unsigned short u[8]; } tmp;
#pragma unroll
                    for (int j = 0; j < 8; j++)
                        tmp.u[j] = (kx + j < edim) ? extra[(size_t)t_st * estride + kx + j] : (unsigned short)0;
                    v = tmp.v4;
                }
            }
            *(uint4*)&As[ar][ac0] = v;
        }
        {   // B stage: W1[k][n] tile, transposed into Bs[n][k]
            int kk = kb + br;
            union { uint4 v4; unsigned short u[8]; } tmp;
            if (kk < ind) tmp.v4 = *(const uint4*)&W1[(size_t)kk * H + n_glob0 + bc0];
            else {
#pragma unroll
                for (int j = 0; j < 8; j++) tmp.u[j] = 0;
            }
#pragma unroll
            for (int j = 0; j < 8; j++) Bs[bc0 + j][br] = tmp.u[j];
        }
        __syncthreads();
        s16x8 a0 = *(const s16x8*)&As[wm * 32 + lrow][kfrag];
        s16x8 a1 = *(const s16x8*)&As[wm * 32 + 16 + lrow][kfrag];
        s16x8 b0 = *(const s16x8*)&Bs[wn * 32 + lrow][kfrag];
        s16x8 b1 = *(const s16x8*)&Bs[wn * 32 + 16 + lrow][kfrag];
        acc[0][0] = __builtin_amdgcn_mfma_f32_16x16x32_bf16(a0, b0, acc[0][0], 0, 0, 0);
        acc[0][1] = __builtin_amdgcn_mfma_f32_16x16x32_bf16(a0, b1, acc[0][1], 0, 0, 0);
        acc[1][0] = __builtin_amdgcn_mfma_f32_16x16x32_bf16(a1, b0, acc[1][0], 0, 0, 0);
        acc[1][1] = __builtin_amdgcn_mfma_f32_16x16x32_bf16(a1, b1, acc[1][1], 0, 0, 0);
        __syncthreads();
    }
#pragma unroll
    for (int mm = 0; mm < 2; mm++) {
#pragma unroll
        for (int i = 0; i < 4; i++) {
            int p = m0 + wm * 32 + mm * 16 + (lane >> 4) * 4 + i;
            if (p < count) {
#pragma unroll
                for (int nn = 0; nn < 2; nn++) {
                    int h = n_glob0 + wn * 32 + nn * 16 + lrow;
                    float val = acc[mm][nn][i] + b2f(bias1[h]);
                    hidden[(size_t)p * H + h] = f2b(gelu_f(val));
                }
            }
        }
    }
}

// ---------------- FFN layer 2: d_out[t] += w * (hidden @ W2 + b2) ----------------
__global__ __launch_bounds__(256) void ffn2_kernel(
    const unsigned short* __restrict__ hidden,
    const unsigned short* __restrict__ W2, const unsigned short* __restrict__ bias2,
    float* __restrict__ outp, int H,
    const int* __restrict__ cnt, int eidx, const int* __restrict__ lists,
    const float* __restrict__ wlists, int rowcap)
{
    int count = cnt[eidx]; if (count > rowcap) count = rowcap;
    const int m0 = blockIdx.x * 64;
    if (m0 >= count) return;
    __shared__ __align__(16) unsigned short As[64][40];
    __shared__ __align__(16) unsigned short Bs[64][40];
    const int tid = threadIdx.x;
    const int ar = tid >> 2, ac0 = (tid & 3) * 8;
    const int p_st = min(m0 + ar, count - 1);
    const unsigned short* arow = hidden + (size_t)p_st * H;
    const int br = tid >> 3, bc0 = (tid & 7) * 8;
    const int lane = tid & 63;
    const int wm = tid >> 7, wn = (tid >> 6) & 1;
    const int lrow = lane & 15, kfrag = (lane >> 4) * 8;
    const int n_glob0 = blockIdx.y * 64;
    fx4 acc[2][2] = {};
    const int nkt = H >> 5;
    for (int kt = 0; kt < nkt; ++kt) {
        const int kb = kt * 32;
        *(uint4*)&As[ar][ac0] = *(const uint4*)&arow[kb + ac0];
        {
            int kk = kb + br;
            union { uint4 v4; unsigned short u[8]; } tmp;
            tmp.v4 = *(const uint4*)&W2[(size_t)kk * DMODEL + n_glob0 + bc0];
#pragma unroll
            for (int j = 0; j < 8; j++) Bs[bc0 + j][br] = tmp.u[j];
        }
        __syncthreads();
        s16x8 a0 = *(const s16x8*)&As[wm * 32 + lrow][kfrag];
        s16x8 a1 = *(const s16x8*)&As[wm * 32 + 16 + lrow][kfrag];
        s16x8 b0 = *(const s16x8*)&Bs[wn * 32 + lrow][kfrag];
        s16x8 b1 = *(const s16x8*)&Bs[wn * 32 + 16 + lrow][kfrag];
        acc[0][0] = __builtin_amdgcn_mfma_f32_16x16x32_bf16(a0, b0, acc[0][0], 0, 0, 0);
        acc[0][1] = __builtin_amdgcn_mfma_f32_16x16x32_bf16(a0, b1, acc[0][1], 0, 0, 0);
        acc[1][0] = __builtin_amdgcn_mfma_f32_16x16x32_bf16(a1, b0, acc[1][0], 0, 0, 0);
        acc[1][1] = __builtin_amdgcn_mfma_f32_16x16x32_bf16(a1, b1, acc[1][1], 0, 0, 0);
        __syncthreads();
    }
#pragma unroll
    for (int mm = 0; mm < 2; mm++) {
#pragma unroll
        for (int i = 0; i < 4; i++) {
            int p = m0 + wm * 32 + mm * 16 + (lane >> 4) * 4 + i;
            if (p < count) {
                int t = lists[eidx * TOK + p];
                float wt = wlists[eidx * TOK + p];
#pragma unroll
                for (int nn = 0; nn < 2; nn++) {
                    int d = n_glob0 + wn * 32 + nn * 16 + lrow;
                    float* dst = &outp[(size_t)t * DMODEL + d];
                    *dst += wt * (acc[mm][nn][i] + b2f(bias2[d]));   // experts serialized on stream: no race
                }
            }
        }
    }
}

// ---------------- aux loss ----------------
__global__ void aux_kernel(float* __restrict__ outp,
                           const int* __restrict__ cnt, const float* __restrict__ Psum) {
    if (threadIdx.x == 0 && blockIdx.x == 0) {
        float aux = 0.f;
#pragma unroll
        for (int e = 0; e < NEXP; e++)
            aux += ((float)cnt[e] / (float)TOK) * (Psum[e] / (float)TOK);
        outp[TOK * DMODEL] = (float)NEXP * aux;
    }
}

extern "C" void kernel_launch(void* const* d_in, const int* in_sizes, int n_in,
                              void* d_out, int out_size, void* d_ws, size_t ws_size,
                              hipStream_t stream)
{
    const float* x       = (const float*)d_in[0];
    const float* flow    = (const float*)d_in[1];
    const float* patches = (const float*)d_in[2];
    const float* deltas  = (const float*)d_in[3];
    const float* qemb    = (const float*)d_in[4];
    const float* Wg      = (const float*)d_in[5];

    unsigned char* ws = (unsigned char*)d_ws;
    int*   cnt    = (int*)(ws);
    float* Psum   = (float*)(ws + 32);
    int*   lists  = (int*)(ws + 1024);
    float* wlists = (float*)(ws + 1024 + (size_t)NEXP * TOK * 4);
    const size_t POOL_OFF = 1024 + 2 * (size_t)NEXP * TOK * 4;   // 525,312
    unsigned short* pool = (unsigned short*)(ws + POOL_OFF);

    // ---- build conversion segment table; lay out bf16 pool ----
    SegTable st;
    int ns = 0;
    size_t cur = 0;
    auto seg = [&](const float* src, size_t n) -> unsigned short* {
        unsigned short* d = pool + cur;
        st.src[ns] = src; st.dst[ns] = d; st.n4[ns] = (int)(n / 4);
        ns++; cur += n;
        return d;
    };
    unsigned short* xb  = seg(x,       (size_t)TOK * DMODEL);
    unsigned short* pb  = seg(patches, (size_t)TOK * 768);
    unsigned short* db  = seg(deltas,  (size_t)TOK * 128);
    unsigned short* fb  = seg(flow,    (size_t)TOK * 2);
    unsigned short* qb  = seg(qemb,    768);
    unsigned short* mW1 = seg((const float*)d_in[6],  770 * 1024);
    unsigned short* mB1 = seg((const float*)d_in[7],  1024);
    unsigned short* mW2 = seg((const float*)d_in[8],  1024 * 768);
    unsigned short* mB2 = seg((const float*)d_in[9],  768);
    unsigned short* tW1 = seg((const float*)d_in[10], 1536 * 1024);
    unsigned short* tB1 = seg((const float*)d_in[11], 1024);
    unsigned short* tW2 = seg((const float*)d_in[12], 1024 * 768);
    unsigned short* tB2 = seg((const float*)d_in[13], 768);
    unsigned short* qW1 = seg((const float*)d_in[14], 1536 * 1024);
    unsigned short* qB1 = seg((const float*)d_in[15], 1024);
    unsigned short* qW2 = seg((const float*)d_in[16], 1024 * 768);
    unsigned short* qB2 = seg((const float*)d_in[17], 768);
    unsigned short* fW1 = seg((const float*)d_in[18], 896 * 1024);
    unsigned short* fB1 = seg((const float*)d_in[19], 1024);
    unsigned short* fW2 = seg((const float*)d_in[20], 1024 * 768);
    unsigned short* fB2 = seg((const float*)d_in[21], 768);
    unsigned short* gW1 = seg((const float*)d_in[22], (size_t)3 * 768 * 3072);
    unsigned short* gB1 = seg((const float*)d_in[23], 3 * 3072);
    unsigned short* gW2 = seg((const float*)d_in[24], (size_t)3 * 3072 * 768);
    unsigned short* gB2 = seg((const float*)d_in[25], 3 * 768);
    unsigned short* zW1 = seg((const float*)d_in[26], 768 * 3072);
    unsigned short* zB1 = seg((const float*)d_in[27], 3072);
    unsigned short* zW2 = seg((const float*)d_in[28], 3072 * 768);
    unsigned short* zB2 = seg((const float*)d_in[29], 768);
    // ns == 29 == NSEG

    const size_t hid_off = POOL_OFF + cur * 2;
    unsigned short* hidden = (unsigned short*)(ws + hid_off);
    long long avail = (long long)ws_size - (long long)hid_off;
    int rowcap = TOK;
    if (avail < (long long)TOK * 3072 * 2) {
        rowcap = (int)(avail / (3072 * 2));
        if (rowcap < 64) rowcap = 64;            // degenerate guard
        if (rowcap > TOK) rowcap = TOK;
    }

    convert_kernel<<<dim3(120, NSEG), 256, 0, stream>>>(st);
    zero_kernel<<<2048, 256, 0, stream>>>((float*)d_out, (unsigned*)ws);
    router_kernel<<<TOK / 4, 256, 0, stream>>>(x, Wg, cnt, Psum, lists, wlists, rowcap);

    struct E { const unsigned short* extra; int edim, estride;
               const unsigned short *W1, *b1, *W2, *b2; int H, ind; };
    E ex[NEXP] = {
        { fb, 2,   2,   mW1, mB1, mW2, mB2, 1024, 770  },
        { pb, 768, 768, tW1, tB1, tW2, tB2, 1024, 1536 },
        { nullptr, 0, 0, zW1, zB1, zW2, zB2, 3072, 768 },
        { qb, 768, 0,   qW1, qB1, qW2, qB2, 1024, 1536 },
        { db, 128, 128, fW1, fB1, fW2, fB2, 1024, 896  },
        { nullptr, 0, 0, gW1 + 0 * (size_t)768 * 3072, gB1 + 0 * 3072, gW2 + 0 * (size_t)3072 * 768, gB2 + 0 * 768, 3072, 768 },
        { nullptr, 0, 0, gW1 + 1 * (size_t)768 * 3072, gB1 + 1 * 3072, gW2 + 1 * (size_t)3072 * 768, gB2 + 1 * 768, 3072, 768 },
        { nullptr, 0, 0, gW1 + 2 * (size_t)768 * 3072, gB1 + 2 * 3072, gW2 + 2 * (size_t)3072 * 768, gB2 + 2 * 768, 3072, 768 },
    };

    for (int e = 0; e < NEXP; e++) {
        dim3 g1(TOK / 64, ex[e].H / 64);
        ffn1_kernel<<<g1, 256, 0, stream>>>(xb, ex[e].extra, ex[e].edim, ex[e].estride,
                                            ex[e].W1, ex[e].b1, hidden, ex[e].H, ex[e].ind,
                                            cnt, e, lists, rowcap);
        dim3 g2(TOK / 64, DMODEL / 64);
        ffn2_kernel<<<g2, 256, 0, stream>>>(hidden, ex[e].W2, ex[e].b2, (float*)d_out, ex[e].H,
                                            cnt, e, lists, wlists, rowcap);
    }
    aux_kernel<<<1, 64, 0, stream>>>((float*)d_out, cnt, Psum);
}

// Round 5
// 1183.720 us; speedup vs baseline: 1.9961x; 1.9961x over previous
//
#include <hip/hip_runtime.h>

#define TOK 8192
#define DMODEL 768
#define NEXP 8
#define NSEG 17
#define NMAT 16

typedef __attribute__((ext_vector_type(8))) short s16x8;
typedef __attribute__((ext_vector_type(4))) short s16x4;
typedef __attribute__((ext_vector_type(4))) float fx4;

__device__ __forceinline__ float b2f(unsigned short u) {
    unsigned v = ((unsigned)u) << 16;
    return __builtin_bit_cast(float, v);
}
__device__ __forceinline__ unsigned short f2b(float f) {
    unsigned v = __builtin_bit_cast(unsigned, f);
    v += 0x7fffu + ((v >> 16) & 1u);
    return (unsigned short)(v >> 16);
}
__device__ __forceinline__ float gelu_f(float v) {
    float g = 0.7978845608028654f * (v + 0.044715f * v * v * v);
    float e = __expf(2.f * g);
    float th = 1.f - 2.f / (e + 1.f);   // overflow-safe tanh
    return 0.5f * v * (1.f + th);
}

struct SegTable {
    const float* src[NSEG];
    unsigned short* dst[NSEG];
    int n4[NSEG];
};

// ---------------- fp32 -> bf16 conversion (vectors + biases) ----------------
__global__ __launch_bounds__(256) void convert_kernel(SegTable st) {
    const int sg = blockIdx.y;
    const float4* __restrict__ src = (const float4*)st.src[sg];
    unsigned short* __restrict__ dst = st.dst[sg];
    const int n4 = st.n4[sg];
    for (int i = blockIdx.x * blockDim.x + threadIdx.x; i < n4; i += gridDim.x * blockDim.x) {
        float4 v = src[i];
        unsigned r0 = (unsigned)f2b(v.x) | ((unsigned)f2b(v.y) << 16);
        unsigned r1 = (unsigned)f2b(v.z) | ((unsigned)f2b(v.w) << 16);
        *(uint2*)&dst[(size_t)i * 4] = make_uint2(r0, r1);
    }
}

// ---------------- fp32 [K][N] -> bf16 [N][Kpad] transpose (weights) ----------------
struct TransTable {
    const float* src[NMAT];
    unsigned short* dst[NMAT];
    int K[NMAT], N[NMAT], Kp[NMAT], base[NMAT];
};

__global__ __launch_bounds__(256) void transpose_kernel(TransTable tt) {
    const int bid = blockIdx.x;
    int m = 0;
#pragma unroll
    for (int i = 1; i < NMAT; i++) if (bid >= tt.base[i]) m = i;
    const int lt = bid - tt.base[m];
    const int ktiles = tt.Kp[m] >> 6;
    const int tk = lt % ktiles, tn = lt / ktiles;
    const int k0 = tk * 64, n0 = tn * 64;
    const float* __restrict__ src = tt.src[m];
    const int K = tt.K[m], N = tt.N[m], Kp = tt.Kp[m];
    __shared__ unsigned short t2[64][72];
    const int tid = threadIdx.x;
    const int kb4 = (tid >> 4) * 4;   // k sub-block (0..60)
    const int c4 = (tid & 15) * 4;    // n sub-block (0..60)
    unsigned short q[4][4];
#pragma unroll
    for (int kk = 0; kk < 4; kk++) {
        int k = k0 + kb4 + kk;
        float4 v = make_float4(0.f, 0.f, 0.f, 0.f);
        if (k < K) v = *(const float4*)&src[(size_t)k * N + n0 + c4];
        q[kk][0] = f2b(v.x); q[kk][1] = f2b(v.y); q[kk][2] = f2b(v.z); q[kk][3] = f2b(v.w);
    }
#pragma unroll
    for (int j = 0; j < 4; j++) {
        s16x4 v4 = { (short)q[0][j], (short)q[1][j], (short)q[2][j], (short)q[3][j] };
        *(s16x4*)&t2[c4 + j][kb4] = v4;
    }
    __syncthreads();
    const int nl = tid >> 2, kc = (tid & 3) * 16;
    uint4 w0 = *(const uint4*)&t2[nl][kc];
    uint4 w1 = *(const uint4*)&t2[nl][kc + 8];
    unsigned short* dr = &tt.dst[m][(size_t)(n0 + nl) * Kp + k0 + kc];
    *(uint4*)&dr[0] = w0;
    *(uint4*)&dr[8] = w1;
}

// ---------------- zero d_out + counters ----------------
__global__ __launch_bounds__(256) void zero_kernel(float* __restrict__ out,
                                                   unsigned* __restrict__ hdr) {
    int idx = blockIdx.x * blockDim.x + threadIdx.x;
    if (blockIdx.x == 0 && threadIdx.x < 16) hdr[threadIdx.x] = 0u;  // cnt[8] + Psum[8]
    float4 z = make_float4(0.f, 0.f, 0.f, 0.f);
    float4* p = (float4*)out;
    const int n4 = TOK * DMODEL / 4;
    for (int i = idx; i < n4; i += gridDim.x * blockDim.x) p[i] = z;
}

// ---------------- router: LDS-aggregated (64 blocks x 128 tokens) ----------------
__global__ __launch_bounds__(256) void router_kernel(
    const float* __restrict__ x, const float* __restrict__ Wg,
    int* __restrict__ cnt, float* __restrict__ Psum,
    int* __restrict__ lists, float* __restrict__ wlists)
{
    __shared__ int llist_t[NEXP][128];
    __shared__ float llist_w[NEXP][128];
    __shared__ int lcnt[NEXP];
    __shared__ float wpsum[4][NEXP];
    __shared__ int lbase[NEXP];
    const int tid = threadIdx.x;
    const int wave = tid >> 6, lane = tid & 63;
    if (tid < NEXP) lcnt[tid] = 0;
    __syncthreads();

    float pacc[NEXP];
#pragma unroll
    for (int e = 0; e < NEXP; e++) pacc[e] = 0.f;

    for (int it = 0; it < 32; ++it) {
        const int t = blockIdx.x * 128 + it * 4 + wave;
        const float* xr = x + (size_t)t * DMODEL;
        float s[NEXP];
#pragma unroll
        for (int e = 0; e < NEXP; e++) s[e] = 0.f;
#pragma unroll
        for (int i = 0; i < 12; i++) {
            int d = lane + 64 * i;
            float xv = xr[d];
            float4 w0 = *(const float4*)&Wg[d * 8];
            float4 w1 = *(const float4*)&Wg[d * 8 + 4];
            s[0] += xv * w0.x; s[1] += xv * w0.y; s[2] += xv * w0.z; s[3] += xv * w0.w;
            s[4] += xv * w1.x; s[5] += xv * w1.y; s[6] += xv * w1.z; s[7] += xv * w1.w;
        }
#pragma unroll
        for (int off = 32; off >= 1; off >>= 1) {
#pragma unroll
            for (int e = 0; e < NEXP; e++) s[e] += __shfl_xor(s[e], off, 64);
        }
        if (lane == 0) {
            float m = s[0];
#pragma unroll
            for (int e = 1; e < NEXP; e++) m = fmaxf(m, s[e]);
            float p[NEXP]; float sum = 0.f;
#pragma unroll
            for (int e = 0; e < NEXP; e++) { p[e] = __expf(s[e] - m); sum += p[e]; }
            float inv = 1.f / sum;
#pragma unroll
            for (int e = 0; e < NEXP; e++) { p[e] *= inv; pacc[e] += p[e]; }
            int i0 = 0;
            for (int e = 1; e < NEXP; e++) if (p[e] > p[i0]) i0 = e;
            int i1 = (i0 == 0) ? 1 : 0;
            for (int e = 0; e < NEXP; e++) if (e != i0 && p[e] > p[i1]) i1 = e;
            float wsum = p[i0] + p[i1];
            int pos0 = atomicAdd(&lcnt[i0], 1);
            llist_t[i0][pos0] = t; llist_w[i0][pos0] = p[i0] / wsum;
            int pos1 = atomicAdd(&lcnt[i1], 1);
            llist_t[i1][pos1] = t; llist_w[i1][pos1] = p[i1] / wsum;
        }
    }
    if (lane == 0) {
#pragma unroll
        for (int e = 0; e < NEXP; e++) wpsum[wave][e] = pacc[e];
    }
    __syncthreads();
    if (tid < NEXP) {
        float tot = wpsum[0][tid] + wpsum[1][tid] + wpsum[2][tid] + wpsum[3][tid];
        atomicAdd(&Psum[tid], tot);
        lbase[tid] = atomicAdd(&cnt[tid], lcnt[tid]);
    }
    __syncthreads();
    for (int idx = tid; idx < NEXP * 128; idx += 256) {
        int e = idx >> 7, j = idx & 127;
        if (j < lcnt[e]) {
            lists[e * TOK + lbase[e] + j]  = llist_t[e][j];
            wlists[e * TOK + lbase[e] + j] = llist_w[e][j];
        }
    }
}

// ---------------- FFN layer 1: hidden = gelu(concat(x,extra) @ W1 + b1), 128x128 tile ----------------
__global__ __launch_bounds__(256) void ffn1_kernel(
    const unsigned short* __restrict__ xb, const unsigned short* __restrict__ extra,
    int edim, int estride,
    const unsigned short* __restrict__ W1T, const unsigned short* __restrict__ b1,
    unsigned short* __restrict__ hidden, int H, int ind, int Kpad,
    const int* __restrict__ cnt, int eidx, const int* __restrict__ lists)
{
    const int count = cnt[eidx];
    const int m0 = blockIdx.x * 128;
    if (m0 >= count) return;
    __shared__ __align__(16) unsigned short As[128][40];
    __shared__ __align__(16) unsigned short Bs[128][40];
    const int tid = threadIdx.x, lane = tid & 63;
    const int wm = tid >> 7, wn = (tid >> 6) & 1;
    const int lrow = lane & 15, kfrag = (lane >> 4) * 8;
    const int sr = tid >> 1, sk = (tid & 1) * 16;
    const int t_r = lists[eidx * TOK + min(m0 + sr, count - 1)];
    const int n0 = blockIdx.y * 128;
    const unsigned short* brow0 = &W1T[(size_t)(n0 + sr) * Kpad];
    fx4 acc[4][4] = {};
    for (int kb = 0; kb < Kpad; kb += 32) {
        uint4 va[2];
#pragma unroll
        for (int u = 0; u < 2; u++) {
            const int k = kb + sk + u * 8;
            if (k + 8 <= DMODEL) {
                va[u] = *(const uint4*)&xb[(size_t)t_r * DMODEL + k];
            } else if (k >= ind) {
                va[u] = make_uint4(0u, 0u, 0u, 0u);
            } else {
                const int kx = k - DMODEL;
                if (kx + 8 <= edim) {
                    va[u] = *(const uint4*)&extra[(size_t)t_r * estride + kx];
                } else {
                    union { uint4 v4; unsigned short s[8]; } tmp;
#pragma unroll
                    for (int j = 0; j < 8; j++) {
                        int kk = k + j;
                        int kxx = kk - DMODEL;
                        tmp.s[j] = (kxx < edim && kk < ind)
                                     ? extra[(size_t)t_r * estride + kxx] : (unsigned short)0;
                    }
                    va[u] = tmp.v4;
                }
            }
        }
        *(uint4*)&As[sr][sk]     = va[0];
        *(uint4*)&As[sr][sk + 8] = va[1];
        *(uint4*)&Bs[sr][sk]     = *(const uint4*)&brow0[kb + sk];
        *(uint4*)&Bs[sr][sk + 8] = *(const uint4*)&brow0[kb + sk + 8];
        __syncthreads();
        s16x8 af[4], bf[4];
#pragma unroll
        for (int m = 0; m < 4; m++) af[m] = *(const s16x8*)&As[wm * 64 + m * 16 + lrow][kfrag];
#pragma unroll
        for (int n = 0; n < 4; n++) bf[n] = *(const s16x8*)&Bs[wn * 64 + n * 16 + lrow][kfrag];
#pragma unroll
        for (int m = 0; m < 4; m++)
#pragma unroll
            for (int n = 0; n < 4; n++)
                acc[m][n] = __builtin_amdgcn_mfma_f32_16x16x32_bf16(af[m], bf[n], acc[m][n], 0, 0, 0);
        __syncthreads();
    }
    float bh[4];
#pragma unroll
    for (int n = 0; n < 4; n++) bh[n] = b2f(b1[n0 + wn * 64 + n * 16 + lrow]);
    const int prow_base = m0 + wm * 64 + (lane >> 4) * 4;
#pragma unroll
    for (int m = 0; m < 4; m++) {
#pragma unroll
        for (int i = 0; i < 4; i++) {
            const int p = prow_base + m * 16 + i;
            if (p < count) {
#pragma unroll
                for (int n = 0; n < 4; n++) {
                    const int h = n0 + wn * 64 + n * 16 + lrow;
                    hidden[(size_t)p * H + h] = f2b(gelu_f(acc[m][n][i] + bh[n]));
                }
            }
        }
    }
}

// ---------------- FFN layer 2: d_out[t] += w * (hidden @ W2 + b2), 128x128 tile ----------------
__global__ __launch_bounds__(256) void ffn2_kernel(
    const unsigned short* __restrict__ hidden,
    const unsigned short* __restrict__ W2T, const unsigned short* __restrict__ b2,
    float* __restrict__ outp, int H,
    const int* __restrict__ cnt, int eidx, const int* __restrict__ lists,
    const float* __restrict__ wlists)
{
    const int count = cnt[eidx];
    const int m0 = blockIdx.x * 128;
    if (m0 >= count) return;
    __shared__ __align__(16) unsigned short As[128][40];
    __shared__ __align__(16) unsigned short Bs[128][40];
    const int tid = threadIdx.x, lane = tid & 63;
    const int wm = tid >> 7, wn = (tid >> 6) & 1;
    const int lrow = lane & 15, kfrag = (lane >> 4) * 8;
    const int sr = tid >> 1, sk = (tid & 1) * 16;
    const int p_st = min(m0 + sr, count - 1);
    const unsigned short* arow = hidden + (size_t)p_st * H;
    const int n0 = blockIdx.y * 128;
    const unsigned short* brow0 = &W2T[(size_t)(n0 + sr) * H];
    fx4 acc[4][4] = {};
    for (int kb = 0; kb < H; kb += 32) {
        *(uint4*)&As[sr][sk]     = *(const uint4*)&arow[kb + sk];
        *(uint4*)&As[sr][sk + 8] = *(const uint4*)&arow[kb + sk + 8];
        *(uint4*)&Bs[sr][sk]     = *(const uint4*)&brow0[kb + sk];
        *(uint4*)&Bs[sr][sk + 8] = *(const uint4*)&brow0[kb + sk + 8];
        __syncthreads();
        s16x8 af[4], bf[4];
#pragma unroll
        for (int m = 0; m < 4; m++) af[m] = *(const s16x8*)&As[wm * 64 + m * 16 + lrow][kfrag];
#pragma unroll
        for (int n = 0; n < 4; n++) bf[n] = *(const s16x8*)&Bs[wn * 64 + n * 16 + lrow][kfrag];
#pragma unroll
        for (int m = 0; m < 4; m++)
#pragma unroll
            for (int n = 0; n < 4; n++)
                acc[m][n] = __builtin_amdgcn_mfma_f32_16x16x32_bf16(af[m], bf[n], acc[m][n], 0, 0, 0);
        __syncthreads();
    }
    float bd[4];
#pragma unroll
    for (int n = 0; n < 4; n++) bd[n] = b2f(b2[n0 + wn * 64 + n * 16 + lrow]);
    const int prow_base = m0 + wm * 64 + (lane >> 4) * 4;
#pragma unroll
    for (int m = 0; m < 4; m++) {
#pragma unroll
        for (int i = 0; i < 4; i++) {
            const int p = prow_base + m * 16 + i;
            if (p < count) {
                const int t = lists[eidx * TOK + p];
                const float wt = wlists[eidx * TOK + p];
#pragma unroll
                for (int n = 0; n < 4; n++) {
                    const int d = n0 + wn * 64 + n * 16 + lrow;
                    outp[(size_t)t * DMODEL + d] += wt * (acc[m][n][i] + bd[n]);  // experts serialized on stream
                }
            }
        }
    }
}

// ---------------- aux loss ----------------
__global__ void aux_kernel(float* __restrict__ outp,
                           const int* __restrict__ cnt, const float* __restrict__ Psum) {
    if (threadIdx.x == 0 && blockIdx.x == 0) {
        float aux = 0.f;
#pragma unroll
        for (int e = 0; e < NEXP; e++)
            aux += ((float)cnt[e] / (float)TOK) * (Psum[e] / (float)TOK);
        outp[TOK * DMODEL] = (float)NEXP * aux;
    }
}

extern "C" void kernel_launch(void* const* d_in, const int* in_sizes, int n_in,
                              void* d_out, int out_size, void* d_ws, size_t ws_size,
                              hipStream_t stream)
{
    const float* x       = (const float*)d_in[0];
    const float* flow    = (const float*)d_in[1];
    const float* patches = (const float*)d_in[2];
    const float* deltas  = (const float*)d_in[3];
    const float* qemb    = (const float*)d_in[4];
    const float* Wg      = (const float*)d_in[5];

    unsigned char* ws = (unsigned char*)d_ws;
    int*   cnt    = (int*)(ws);
    float* Psum   = (float*)(ws + 32);
    int*   lists  = (int*)(ws + 1024);
    float* wlists = (float*)(ws + 1024 + (size_t)NEXP * TOK * 4);
    const size_t POOL_OFF = 1024 + 2 * (size_t)NEXP * TOK * 4;   // 525,312
    unsigned short* pool = (unsigned short*)(ws + POOL_OFF);
    size_t cur = 0;

    // ---- convert segments (vectors + biases) ----
    SegTable st; int ns = 0;
    auto seg = [&](const float* src, size_t n) -> unsigned short* {
        unsigned short* d = pool + cur;
        st.src[ns] = src; st.dst[ns] = d; st.n4[ns] = (int)(n / 4);
        ns++; cur += n;
        return d;
    };
    unsigned short* xb  = seg(x,       (size_t)TOK * DMODEL);
    unsigned short* pb  = seg(patches, (size_t)TOK * 768);
    unsigned short* db  = seg(deltas,  (size_t)TOK * 128);
    unsigned short* fb  = seg(flow,    (size_t)TOK * 2);
    unsigned short* qb  = seg(qemb,    768);
    unsigned short* mB1 = seg((const float*)d_in[7],  1024);
    unsigned short* mB2 = seg((const float*)d_in[9],  768);
    unsigned short* tB1 = seg((const float*)d_in[11], 1024);
    unsigned short* tB2 = seg((const float*)d_in[13], 768);
    unsigned short* qB1 = seg((const float*)d_in[15], 1024);
    unsigned short* qB2 = seg((const float*)d_in[17], 768);
    unsigned short* fB1 = seg((const float*)d_in[19], 1024);
    unsigned short* fB2 = seg((const float*)d_in[21], 768);
    unsigned short* gB1 = seg((const float*)d_in[23], 3 * 3072);
    unsigned short* gB2 = seg((const float*)d_in[25], 3 * 768);
    unsigned short* zB1 = seg((const float*)d_in[27], 3072);
    unsigned short* zB2 = seg((const float*)d_in[29], 768);
    // ns == 17 == NSEG

    // ---- transpose segments (weights -> [N][Kpad] bf16) ----
    TransTable tt; int nm = 0; int tiles = 0;
    auto tseg = [&](const float* src, int K, int N, int Kp) -> unsigned short* {
        unsigned short* d = pool + cur;
        tt.src[nm] = src; tt.dst[nm] = d;
        tt.K[nm] = K; tt.N[nm] = N; tt.Kp[nm] = Kp; tt.base[nm] = tiles;
        tiles += (N / 64) * (Kp / 64);
        nm++; cur += (size_t)N * Kp;
        return d;
    };
    unsigned short* mW1T = tseg((const float*)d_in[6],  770,  1024, 832);
    unsigned short* tW1T = tseg((const float*)d_in[10], 1536, 1024, 1536);
    unsigned short* qW1T = tseg((const float*)d_in[14], 1536, 1024, 1536);
    unsigned short* fW1T = tseg((const float*)d_in[18], 896,  1024, 896);
    unsigned short* zW1T = tseg((const float*)d_in[26], 768,  3072, 768);
    unsigned short* gW1T0 = tseg((const float*)d_in[22] + 0 * (size_t)768 * 3072, 768, 3072, 768);
    unsigned short* gW1T1 = tseg((const float*)d_in[22] + 1 * (size_t)768 * 3072, 768, 3072, 768);
    unsigned short* gW1T2 = tseg((const float*)d_in[22] + 2 * (size_t)768 * 3072, 768, 3072, 768);
    unsigned short* mW2T = tseg((const float*)d_in[8],  1024, 768, 1024);
    unsigned short* tW2T = tseg((const float*)d_in[12], 1024, 768, 1024);
    unsigned short* qW2T = tseg((const float*)d_in[16], 1024, 768, 1024);
    unsigned short* fW2T = tseg((const float*)d_in[20], 1024, 768, 1024);
    unsigned short* zW2T = tseg((const float*)d_in[28], 3072, 768, 3072);
    unsigned short* gW2T0 = tseg((const float*)d_in[24] + 0 * (size_t)3072 * 768, 3072, 768, 3072);
    unsigned short* gW2T1 = tseg((const float*)d_in[24] + 1 * (size_t)3072 * 768, 3072, 768, 3072);
    unsigned short* gW2T2 = tseg((const float*)d_in[24] + 2 * (size_t)3072 * 768, 3072, 768, 3072);
    // nm == 16 == NMAT, tiles == 6576

    unsigned short* hidden = (unsigned short*)(ws + POOL_OFF + cur * 2);

    convert_kernel<<<dim3(256, NSEG), 256, 0, stream>>>(st);
    transpose_kernel<<<tiles, 256, 0, stream>>>(tt);
    zero_kernel<<<2048, 256, 0, stream>>>((float*)d_out, (unsigned*)ws);
    router_kernel<<<TOK / 128, 256, 0, stream>>>(x, Wg, cnt, Psum, lists, wlists);

    struct E { const unsigned short* extra; int edim, estride;
               const unsigned short *W1T, *b1, *W2T, *b2; int H, ind, Kpad; };
    E ex[NEXP] = {
        { fb, 2,   2,   mW1T, mB1, mW2T, mB2, 1024, 770,  832  },
        { pb, 768, 768, tW1T, tB1, tW2T, tB2, 1024, 1536, 1536 },
        { nullptr, 0, 0, zW1T, zB1, zW2T, zB2, 3072, 768, 768 },
        { qb, 768, 0,   qW1T, qB1, qW2T, qB2, 1024, 1536, 1536 },
        { db, 128, 128, fW1T, fB1, fW2T, fB2, 1024, 896,  896  },
        { nullptr, 0, 0, gW1T0, gB1 + 0 * 3072, gW2T0, gB2 + 0 * 768, 3072, 768, 768 },
        { nullptr, 0, 0, gW1T1, gB1 + 1 * 3072, gW2T1, gB2 + 1 * 768, 3072, 768, 768 },
        { nullptr, 0, 0, gW1T2, gB1 + 2 * 3072, gW2T2, gB2 + 2 * 768, 3072, 768, 768 },
    };

    for (int e = 0; e < NEXP; e++) {
        dim3 g1(TOK / 128, ex[e].H / 128);
        ffn1_kernel<<<g1, 256, 0, stream>>>(xb, ex[e].extra, ex[e].edim, ex[e].estride,
                                            ex[e].W1T, ex[e].b1, hidden, ex[e].H, ex[e].ind, ex[e].Kpad,
                                            cnt, e, lists);
        dim3 g2(TOK / 128, DMODEL / 128);
        ffn2_kernel<<<g2, 256, 0, stream>>>(hidden, ex[e].W2T, ex[e].b2, (float*)d_out, ex[e].H,
                                            cnt, e, lists, wlists);
    }
    aux_kernel<<<1, 64, 0, stream>>>((float*)d_out, cnt, Psum);
}